// Round 8
// baseline (150.900 us; speedup 1.0000x reference)
//
#include <hip/hip_runtime.h>
#include <math.h>

typedef __attribute__((ext_vector_type(8))) short short8;
typedef __attribute__((ext_vector_type(4))) float f32x4;

#define B_  16
#define T_  4096
#define C_  64
#define KE_ 1023
#define BT_ (B_ * T_)
// guard in d/2-space: == baseline's 1e-3 in d-space; >= 3x provable bf16-split err
#define WINHALF 5e-4f

// ---------------- ws layout (bytes) ----------------
// [0,       64)      int   flagcnt
// [64,      4160)    float ee[1024]        (|e_k|^2 raw, for k_fix; ee[1023]=+inf)
// [4224,    135296)  u16   Eh[1024*64]     (bf16 hi of NEGATED codebook[1:])
// [135296,  266368)  u16   El[1024*64]     (bf16 lo residual of NEGATED codebook)
// [266368,  528512)  int   kbest[BT]
// [528512,  790656)  int   selpos[BT]
// [790656,  790720)  int   nst[B]
// [791680,  795776)  float commit_part[1024]
// [795776,  799872)  float valid_part[1024]
// [799872,  803968)  float smooth_part[1024]
// [804032,  1066176) int   flaglist[BT]
// [1066176, 1070272) float ee2[1024]       (0.5 + |e_k|^2/2 for C-init; [1023]=+inf)

__device__ __forceinline__ unsigned short f2bf(float x) {
    unsigned int u = __float_as_uint(x);
    unsigned int r = (u + 0x7FFFu + ((u >> 16) & 1u)) >> 16;   // RNE
    return (unsigned short)r;
}
__device__ __forceinline__ float bf2f(unsigned short h) {
    return __uint_as_float(((unsigned int)h) << 16);
}

typedef __attribute__((address_space(1))) const unsigned int g_u32;
typedef __attribute__((address_space(3))) unsigned int l_u32;
__device__ __forceinline__ void gload16(const void* g, void* l) {
    // dest = wave-uniform LDS base + lane*16B; src is per-lane global addr
    __builtin_amdgcn_global_load_lds((g_u32*)g, (l_u32*)l, 16, 0, 0);
}

// ---- prep: ee, ee2, bf16 hi/lo of NEGATED codebook, flagcnt=0 ----
__global__ __launch_bounds__(64) void k_prep(const float* __restrict__ cb,
                                             float* __restrict__ ee,
                                             float* __restrict__ ee2,
                                             unsigned short* __restrict__ Eh,
                                             unsigned short* __restrict__ El,
                                             int* __restrict__ flagcnt) {
    const int k = blockIdx.x * 64 + threadIdx.x;   // 0..1023
    if (k == 0) *flagcnt = 0;
    unsigned int* EhU = (unsigned int*)Eh;
    unsigned int* ElU = (unsigned int*)El;
    if (k < KE_) {
        const float* r = cb + (size_t)(k + 1) * C_;
        float s = 0.f;
        #pragma unroll
        for (int c = 0; c < C_; c += 2) {
            const float x0 = r[c], x1 = r[c + 1];
            s = fmaf(x0, x0, s);
            s = fmaf(x1, x1, s);
            const float n0 = -x0, n1 = -x1;            // negated codebook
            const unsigned short h0 = f2bf(n0), h1 = f2bf(n1);
            const unsigned short l0 = f2bf(n0 - bf2f(h0));
            const unsigned short l1 = f2bf(n1 - bf2f(h1));
            EhU[k * 32 + c / 2] = (unsigned int)h0 | ((unsigned int)h1 << 16);
            ElU[k * 32 + c / 2] = (unsigned int)l0 | ((unsigned int)l1 << 16);
        }
        ee[k]  = s;
        ee2[k] = 0.5f + 0.5f * s;      // acc init => acc_final = d/2
    } else {        // k == 1023 pad: zero rows, inf distance
        #pragma unroll
        for (int c = 0; c < 32; ++c) { EhU[k * 32 + c] = 0u; ElU[k * 32 + c] = 0u; }
        ee[k]  = INFINITY;
        ee2[k] = INFINITY;
    }
}

// ---- hot kernel: R8 = R5 wave structure (32q/wave) at R3 occupancy ----
// 512-thread blocks, 8 waves x 32q (BQ=256), grid 256, LDS 66.5KB ->
// 2 blocks/CU -> 16 waves/CU = 4 waves/SIMD (2x R5's TLP) AND half the
// codebook re-staging (256 vs 512 block-passes). Staging macro = R3's
// verified 512-thread geometry; compute/flag path = R5/R7 verbatim.
__global__ __launch_bounds__(512, 4) void k_assign(
    const float* __restrict__ z, const unsigned short* __restrict__ Eh,
    const unsigned short* __restrict__ El, const float* __restrict__ ee2,
    int* __restrict__ kbest, int* __restrict__ flaglist,
    int* __restrict__ flagcnt) {

    __shared__ __align__(16) unsigned short s_eh[2][128 * 64];
    __shared__ __align__(16) unsigned short s_el[2][128 * 64];
    __shared__ float s_ee[2][128];

    const int tid  = threadIdx.x;        // 0..511
    const int wave = tid >> 6;           // 0..7
    const int lane = tid & 63;
    const int col  = lane & 15;
    const int quad = lane >> 4;
    const int Q0   = blockIdx.x * 256 + wave * 32;

    // ---- A fragments: 32 queries per wave (2 groups of 16), hi/lo ----
    short8 ah[2][2], al[2][2];
    #pragma unroll
    for (int g = 0; g < 2; ++g) {
        const float4* zp = (const float4*)(z + (size_t)(Q0 + g * 16 + col) * C_);
        const float4 f0 = zp[quad * 2];
        const float4 f1 = zp[quad * 2 + 1];
        const float4 f2 = zp[8 + quad * 2];
        const float4 f3 = zp[8 + quad * 2 + 1];
        float xs[16] = {f0.x, f0.y, f0.z, f0.w, f1.x, f1.y, f1.z, f1.w,
                        f2.x, f2.y, f2.z, f2.w, f3.x, f3.y, f3.z, f3.w};
        float ss = 0.f;
        #pragma unroll
        for (int i = 0; i < 16; ++i) ss = fmaf(xs[i], xs[i], ss);
        ss += __shfl_xor(ss, 16);
        ss += __shfl_xor(ss, 32);
        const float inv = 1.f / fmaxf(sqrtf(ss), 1e-12f);
        short8 h0, h1, l0, l1;
        #pragma unroll
        for (int i = 0; i < 8; ++i) {
            const float x = xs[i] * inv;
            const unsigned short hx = f2bf(x);
            h0[i] = (short)hx;
            l0[i] = (short)f2bf(x - bf2f(hx));
            const float y = xs[8 + i] * inv;
            const unsigned short hy = f2bf(y);
            h1[i] = (short)hy;
            l1[i] = (short)f2bf(y - bf2f(hy));
        }
        ah[g][0] = h0; ah[g][1] = h1;
        al[g][0] = l0; al[g][1] = l1;
    }

    // exact fp32 top-2 (value + index) in d/2-space
    float bestv[2][4], secv[2][4];
    int   bkk[2][4];
    #pragma unroll
    for (int g = 0; g < 2; ++g)
        #pragma unroll
        for (int r = 0; r < 4; ++r) {
            bestv[g][r] = INFINITY; secv[g][r] = INFINITY; bkk[g][r] = 0;
        }

    // staging geometry (512 threads, verified R3): round j covers 64 rows.
    const int srow = tid >> 3;                    // 0..63 (row within round)
    const int schk = (tid & 7) ^ (srow & 7);      // pre-swizzled source chunk
    const int ldsb = wave * 512;                  // wave-uniform LDS base (shorts)

#define STAGE_J(tt, bb, j) do {                                                \
        const size_t go = (size_t)((tt) * 128 + (j) * 64 + srow) * 64          \
                          + (size_t)schk * 8;                                  \
        gload16(Eh + go, (void*)&s_eh[bb][(j) * 4096 + ldsb]);                 \
        gload16(El + go, (void*)&s_el[bb][(j) * 4096 + ldsb]);                 \
    } while (0)

    int cur = 0;
    STAGE_J(0, 0, 0); STAGE_J(0, 0, 1);
    if (tid < 128) s_ee[0][tid] = ee2[tid];
    __syncthreads();                 // drains vmcnt(0): tile 0 resident

    const int coff = (quad ^ (col & 7)) * 8;      // swizzled read chunk (shorts)

    for (int t = 0; t < 8; ++t) {
        // first half of next-tile staging: issue immediately after barrier
        if (t < 7) STAGE_J(t + 1, cur ^ 1, 0);

        float ev[8];
        #pragma unroll
        for (int s = 0; s < 8; ++s) ev[s] = s_ee[cur][s * 16 + col];

        // preload s=0 B-fragments into registers
        short8 fh0 = *(const short8*)&s_eh[cur][col * 64 + coff];
        short8 fh1 = *(const short8*)&s_eh[cur][col * 64 + (coff ^ 32)];
        short8 fl0 = *(const short8*)&s_el[cur][col * 64 + coff];
        short8 fl1 = *(const short8*)&s_el[cur][col * 64 + (coff ^ 32)];

        // second half of next-tile staging (spread: no post-barrier burst)
        if (t < 7) {
            STAGE_J(t + 1, cur ^ 1, 1);
            if (tid < 128) s_ee[cur ^ 1][tid] = ee2[(t + 1) * 128 + tid];
        }

        const int kb = t * 128 + col;

        #pragma unroll
        for (int s = 0; s < 8; ++s) {
            // prefetch s+1 fragments (redundant reload of s=7 on last step)
            const int sn = (s < 7) ? (s + 1) : 7;
            const int rb = (sn * 16 + col) * 64;
            short8 nh0 = *(const short8*)&s_eh[cur][rb + coff];
            short8 nh1 = *(const short8*)&s_eh[cur][rb + (coff ^ 32)];
            short8 nl0 = *(const short8*)&s_el[cur][rb + coff];
            short8 nl1 = *(const short8*)&s_el[cur][rb + (coff ^ 32)];

            const float e2 = ev[s];
            f32x4 p0 = {e2, e2, e2, e2};
            f32x4 p1 = {e2, e2, e2, e2};
            __builtin_amdgcn_s_setprio(1);
            // two independent 6-chains, interleaved for MFMA-pipe overlap
            p0 = __builtin_amdgcn_mfma_f32_16x16x32_bf16(ah[0][0], fh0, p0, 0, 0, 0);
            p1 = __builtin_amdgcn_mfma_f32_16x16x32_bf16(ah[1][0], fh0, p1, 0, 0, 0);
            p0 = __builtin_amdgcn_mfma_f32_16x16x32_bf16(ah[0][1], fh1, p0, 0, 0, 0);
            p1 = __builtin_amdgcn_mfma_f32_16x16x32_bf16(ah[1][1], fh1, p1, 0, 0, 0);
            p0 = __builtin_amdgcn_mfma_f32_16x16x32_bf16(ah[0][0], fl0, p0, 0, 0, 0);
            p1 = __builtin_amdgcn_mfma_f32_16x16x32_bf16(ah[1][0], fl0, p1, 0, 0, 0);
            p0 = __builtin_amdgcn_mfma_f32_16x16x32_bf16(ah[0][1], fl1, p0, 0, 0, 0);
            p1 = __builtin_amdgcn_mfma_f32_16x16x32_bf16(ah[1][1], fl1, p1, 0, 0, 0);
            p0 = __builtin_amdgcn_mfma_f32_16x16x32_bf16(al[0][0], fh0, p0, 0, 0, 0);
            p1 = __builtin_amdgcn_mfma_f32_16x16x32_bf16(al[1][0], fh0, p1, 0, 0, 0);
            p0 = __builtin_amdgcn_mfma_f32_16x16x32_bf16(al[0][1], fh1, p0, 0, 0, 0);
            p1 = __builtin_amdgcn_mfma_f32_16x16x32_bf16(al[1][1], fh1, p1, 0, 0, 0);
            __builtin_amdgcn_s_setprio(0);

            const int kc = kb + s * 16;
            #pragma unroll
            for (int r = 0; r < 4; ++r) {
                {
                    const float v  = p0[r];       // = d/2 exactly (fp32)
                    const float bo = bestv[0][r];
                    bkk[0][r]   = (v < bo) ? kc : bkk[0][r];
                    secv[0][r]  = fminf(secv[0][r], fmaxf(bo, v));
                    bestv[0][r] = fminf(bo, v);
                }
                {
                    const float v  = p1[r];
                    const float bo = bestv[1][r];
                    bkk[1][r]   = (v < bo) ? kc : bkk[1][r];
                    secv[1][r]  = fminf(secv[1][r], fmaxf(bo, v));
                    bestv[1][r] = fminf(bo, v);
                }
            }
            fh0 = nh0; fh1 = nh1; fl0 = nl0; fl1 = nl1;
        }
        __syncthreads();             // reads done + next-tile stage drained
        cur ^= 1;
    }
#undef STAGE_J

    #pragma unroll
    for (int g = 0; g < 2; ++g) {
        #pragma unroll
        for (int r = 0; r < 4; ++r) {
            float b  = bestv[g][r], sc = secv[g][r];
            int   k  = bkk[g][r];
            #pragma unroll
            for (int off = 1; off < 16; off <<= 1) {
                const float ob = __shfl_xor(b, off);
                const int   ok = __shfl_xor(k, off);
                const float os = __shfl_xor(sc, off);
                const bool take = (ob < b) || (ob == b && ok < k);
                const float lose = take ? b : ob;
                sc = fminf(fminf(sc, os), lose);
                b  = take ? ob : b;
                k  = take ? ok : k;
            }
            if (col == 0) {
                const int q = Q0 + g * 16 + quad * 4 + r;
                kbest[q] = k;
                if (!(sc - b > WINHALF)) {              // ambiguous -> exact path
                    const int pos = atomicAdd(flagcnt, 1);
                    flaglist[pos] = q;
                }
            }
        }
    }
}

// ---- exact fp32 rescan, BLOCK per flagged query (verified, unchanged) ----
__global__ __launch_bounds__(256) void k_fix(const float* __restrict__ z,
                                             const float* __restrict__ cb,
                                             const float* __restrict__ ee,
                                             const int* __restrict__ flagcnt,
                                             const int* __restrict__ flaglist,
                                             int* __restrict__ kbest) {
    __shared__ float s_z[64];
    __shared__ float s_bv[4];
    __shared__ int   s_bk[4];
    const int tid  = threadIdx.x;
    const int lane = tid & 63;
    const int wave = tid >> 6;
    const int n = *flagcnt;

    for (int i = blockIdx.x; i < n; i += 1024) {
        const int q = flaglist[i];
        __syncthreads();               // s_z reuse guard across iterations
        if (tid < 16) ((float4*)s_z)[tid] = ((const float4*)(z + (size_t)q * C_))[tid];
        __syncthreads();

        float4 zn[16];
        float ss = 0.f;
        #pragma unroll
        for (int c4 = 0; c4 < 16; ++c4) {
            const float4 v = ((const float4*)s_z)[c4];
            zn[c4] = v;
            ss = fmaf(v.x, v.x, ss); ss = fmaf(v.y, v.y, ss);
            ss = fmaf(v.z, v.z, ss); ss = fmaf(v.w, v.w, ss);
        }
        const float nrm = fmaxf(sqrtf(ss), 1e-12f);
        #pragma unroll
        for (int c4 = 0; c4 < 16; ++c4) {
            zn[c4].x /= nrm; zn[c4].y /= nrm; zn[c4].z /= nrm; zn[c4].w /= nrm;
        }

        const int k0 = tid * 4;        // codes k0..k0+3 (k0+3 <= 1023)
        const float4* e0 = (const float4*)(cb + (size_t)(k0 + 1) * C_);
        const float4* e1 = (const float4*)(cb + (size_t)(k0 + 2) * C_);
        const float4* e2 = (const float4*)(cb + (size_t)(k0 + 3) * C_);
        const float4* e3 = (const float4*)(cb + (size_t)((k0 + 4 <= KE_) ? (k0 + 4) : KE_) * C_);
        float d0 = 0.f, d1 = 0.f, d2 = 0.f, d3 = 0.f;
        #pragma unroll
        for (int c4 = 0; c4 < 16; ++c4) {   // in-order fp32 chains
            const float4 x = zn[c4];
            const float4 a = e0[c4], b = e1[c4], c = e2[c4], d = e3[c4];
            d0 = fmaf(x.x, a.x, d0); d0 = fmaf(x.y, a.y, d0);
            d0 = fmaf(x.z, a.z, d0); d0 = fmaf(x.w, a.w, d0);
            d1 = fmaf(x.x, b.x, d1); d1 = fmaf(x.y, b.y, d1);
            d1 = fmaf(x.z, b.z, d1); d1 = fmaf(x.w, b.w, d1);
            d2 = fmaf(x.x, c.x, d2); d2 = fmaf(x.y, c.y, d2);
            d2 = fmaf(x.z, c.z, d2); d2 = fmaf(x.w, c.w, d2);
            d3 = fmaf(x.x, d.x, d3); d3 = fmaf(x.y, d.y, d3);
            d3 = fmaf(x.z, d.z, d3); d3 = fmaf(x.w, d.w, d3);
        }
        float bv = INFINITY;
        int   bk = 0;
        float v;
        v = fmaf(-2.f, d0, ee[k0 + 0]); if (v < bv) { bv = v; bk = k0 + 0; }
        v = fmaf(-2.f, d1, ee[k0 + 1]); if (v < bv) { bv = v; bk = k0 + 1; }
        v = fmaf(-2.f, d2, ee[k0 + 2]); if (v < bv) { bv = v; bk = k0 + 2; }
        v = fmaf(-2.f, d3, ee[k0 + 3]); if (v < bv) { bv = v; bk = k0 + 3; }

        #pragma unroll
        for (int off = 32; off > 0; off >>= 1) {
            const float ov = __shfl_down(bv, off);
            const int   ok = __shfl_down(bk, off);
            if (ov < bv || (ov == bv && ok < bk)) { bv = ov; bk = ok; }
        }
        if (lane == 0) { s_bv[wave] = bv; s_bk[wave] = bk; }
        __syncthreads();
        if (tid == 0) {
            float fb = s_bv[0]; int fk = s_bk[0];
            #pragma unroll
            for (int w = 1; w < 4; ++w) {
                if (s_bv[w] < fb || (s_bv[w] == fb && s_bk[w] < fk)) {
                    fb = s_bv[w]; fk = s_bk[w];
                }
            }
            kbest[q] = fk;
        }
    }
}

// ---- epilogue: z_q, commit/valid partials + ALL smoothness pairs ----
// (verified R7: 4 threads/query, group-15 boundary recompute)
__global__ __launch_bounds__(256) void k_epi(
    const float* __restrict__ z, const float* __restrict__ cb,
    const float* __restrict__ mask, const int* __restrict__ kbest,
    float* __restrict__ zqo,
    float* __restrict__ commit_part, float* __restrict__ valid_part,
    float* __restrict__ smooth_part) {

    __shared__ float s_red[12];
    const int tid  = threadIdx.x;
    const int lane = tid & 63;
    const int wave = tid >> 6;
    const int gt   = blockIdx.x * 256 + tid;
    const int q    = gt >> 2;          // query index
    const int p    = gt & 3;           // 16-column chunk within query
    const int grp  = lane >> 2;        // 0..15 query-group within wave

    const int bi = kbest[q];
    const float m = mask[q];

    const float4* zp = (const float4*)(z + (size_t)q * C_ + p * 16);
    const float4* er = (const float4*)(cb + (size_t)(bi + 1) * C_ + p * 16);
    float4* zo = (float4*)(zqo + (size_t)q * C_ + p * 16);

    float4 zr[4];
    float ss = 0.f;
    #pragma unroll
    for (int i = 0; i < 4; ++i) {
        float4 v = zp[i];
        zr[i] = v;
        ss = fmaf(v.x, v.x, ss); ss = fmaf(v.y, v.y, ss);
        ss = fmaf(v.z, v.z, ss); ss = fmaf(v.w, v.w, ss);
    }
    // norm over the 4-lane group owning this query
    ss += __shfl_xor(ss, 1);
    ss += __shfl_xor(ss, 2);
    const float nrm = fmaxf(sqrtf(ss), 1e-12f);

    float commit = 0.f, sm = 0.f;
    float4 ov[4];
    #pragma unroll
    for (int c4 = 0; c4 < 4; ++c4) {
        const float z0 = zr[c4].x / nrm, z1 = zr[c4].y / nrm;
        const float z2 = zr[c4].z / nrm, z3 = zr[c4].w / nrm;
        const float4 e4 = er[c4];
        const float q0 = e4.x * m, q1 = e4.y * m, q2 = e4.z * m, q3 = e4.w * m;
        float4 o;
        o.x = (z0 + q0) - z0;              // straight-through forward value
        o.y = (z1 + q1) - z1;
        o.z = (z2 + q2) - z2;
        o.w = (z3 + q3) - z3;
        zo[c4] = o;
        ov[c4] = o;
        const float d0 = z0 - q0, d1 = z1 - q1, d2 = z2 - q2, d3 = z3 - q3;
        commit = fmaf(d0, d0, commit); commit = fmaf(d1, d1, commit);
        commit = fmaf(d2, d2, commit); commit = fmaf(d3, d3, commit);
    }
    commit *= m;

    // within-wave pairs (groups 0..14); shfl OOB returns own value -> diff 0
    float mnext = 0.f;
    if (grp != 15) mnext = mask[q + 1];    // q+1 in-range (grp 15 excluded)
    #pragma unroll
    for (int c4 = 0; c4 < 4; ++c4) {
        const float n0 = __shfl_down(ov[c4].x, 4);
        const float n1 = __shfl_down(ov[c4].y, 4);
        const float n2 = __shfl_down(ov[c4].z, 4);
        const float n3 = __shfl_down(ov[c4].w, 4);
        const float x0 = ov[c4].x - n0, x1 = ov[c4].y - n1;
        const float x2 = ov[c4].z - n2, x3 = ov[c4].w - n3;
        sm = fmaf(x0, x0, sm); sm = fmaf(x1, x1, sm);
        sm = fmaf(x2, x2, sm); sm = fmaf(x3, x3, sm);
    }
    sm *= mnext;

    // boundary pair (q, q+1) for group 15: recompute o(q+1) locally.
    // Branch is uniform within the 4-lane group -> interior shfl_xor safe.
    if (grp == 15) {
        float mn = 0.f;
        if ((q & (T_ - 1)) != T_ - 1) mn = mask[q + 1];   // also guards q+1 OOB
        if (mn > 0.f) {
            const int bi2 = kbest[q + 1];
            const float4* zp2 = (const float4*)(z + (size_t)(q + 1) * C_ + p * 16);
            const float4* er2 = (const float4*)(cb + (size_t)(bi2 + 1) * C_ + p * 16);
            float4 zr2[4];
            float s2 = 0.f;
            #pragma unroll
            for (int i = 0; i < 4; ++i) {
                float4 v = zp2[i];
                zr2[i] = v;
                s2 = fmaf(v.x, v.x, s2); s2 = fmaf(v.y, v.y, s2);
                s2 = fmaf(v.z, v.z, s2); s2 = fmaf(v.w, v.w, s2);
            }
            s2 += __shfl_xor(s2, 1);
            s2 += __shfl_xor(s2, 2);
            const float nrm2 = fmaxf(sqrtf(s2), 1e-12f);
            float smb = 0.f;
            #pragma unroll
            for (int c4 = 0; c4 < 4; ++c4) {
                const float w0 = zr2[c4].x / nrm2, w1 = zr2[c4].y / nrm2;
                const float w2 = zr2[c4].z / nrm2, w3 = zr2[c4].w / nrm2;
                const float4 e4 = er2[c4];
                const float a0 = e4.x * mn, a1 = e4.y * mn;
                const float a2 = e4.z * mn, a3 = e4.w * mn;
                const float o0 = (w0 + a0) - w0;   // bitwise == zqo[q+1] chunk
                const float o1 = (w1 + a1) - w1;
                const float o2 = (w2 + a2) - w2;
                const float o3 = (w3 + a3) - w3;
                const float x0 = ov[c4].x - o0, x1 = ov[c4].y - o1;
                const float x2 = ov[c4].z - o2, x3 = ov[c4].w - o3;
                smb = fmaf(x0, x0, smb); smb = fmaf(x1, x1, smb);
                smb = fmaf(x2, x2, smb); smb = fmaf(x3, x3, smb);
            }
            sm = smb * mn;
        }
    }

    float vc = (p == 0) ? m : 0.f;     // count each query once
    #pragma unroll
    for (int off = 32; off > 0; off >>= 1) {
        commit += __shfl_down(commit, off);
        vc     += __shfl_down(vc, off);
        sm     += __shfl_down(sm, off);
    }
    if (lane == 0) { s_red[wave] = commit; s_red[4 + wave] = vc; s_red[8 + wave] = sm; }
    __syncthreads();
    if (tid == 0) {
        commit_part[blockIdx.x] = s_red[0] + s_red[1] + s_red[2] + s_red[3];
        valid_part[blockIdx.x]  = s_red[4] + s_red[5] + s_red[6] + s_red[7];
        smooth_part[blockIdx.x] = s_red[8] + s_red[9] + s_red[10] + s_red[11];
    }
}

// ---- per-batch start compaction (pure; verified R7) ----
__global__ __launch_bounds__(256) void k_scan(const int* __restrict__ kbest,
                                              const float* __restrict__ mask,
                                              int* __restrict__ selpos,
                                              int* __restrict__ nst) {
    __shared__ int cnt[256];
    const int b = blockIdx.x;
    const int tid = threadIdx.x;
    const int base = b * T_;
    const int t0 = tid * 16;

    int flags = 0, c = 0;
    int prev = (tid == 0) ? -1 : kbest[base + t0 - 1];
    #pragma unroll
    for (int i = 0; i < 16; ++i) {
        const int t = t0 + i;
        const int cur = kbest[base + t];
        const int is = (t == 0) ? 1
                     : ((cur != prev && mask[base + t] > 0.f) ? 1 : 0);
        flags |= is << i;
        c += is;
        prev = cur;
    }
    cnt[tid] = c;
    __syncthreads();
    for (int off = 1; off < 256; off <<= 1) {
        int add = (tid >= off) ? cnt[tid - off] : 0;
        __syncthreads();
        cnt[tid] += add;
        __syncthreads();
    }
    int pos = cnt[tid] - c;   // exclusive prefix
    #pragma unroll
    for (int i = 0; i < 16; ++i) {
        if ((flags >> i) & 1) selpos[base + pos++] = t0 + i;
    }
    if (tid == 255) nst[b] = cnt[255];
}

// ---- fused n_z_q gather + n_mask + selected_encodings + loss finalize ----
__global__ __launch_bounds__(256) void k_gsel(const float* __restrict__ zqo,
                                              const int* __restrict__ kbest,
                                              const int* __restrict__ selpos,
                                              const int* __restrict__ nst,
                                              const float* __restrict__ commit_part,
                                              const float* __restrict__ valid_part,
                                              const float* __restrict__ smooth_part,
                                              float* __restrict__ nzq,
                                              float* __restrict__ nmask,
                                              float* __restrict__ sel,
                                              float* __restrict__ out) {
    const int gid = blockIdx.x * 256 + threadIdx.x;   // float4 index
    const int b   = gid >> 16;          // T*C/4 = 65536 float4 per batch
    const int rem = gid & 65535;
    const int j   = rem >> 4;
    const int c4  = rem & 15;
    const int n   = nst[b];
    float4 v = make_float4(0.f, 0.f, 0.f, 0.f);
    int p = 0;
    if (j < n) {
        p = selpos[b * T_ + j];
        v = ((const float4*)zqo)[((size_t)b * T_ + p) * 16 + c4];
    }
    ((float4*)nzq)[gid] = v;
    if (c4 == 0) {
        float nm = 0.f, s = 0.f;
        if (j < n) { nm = 1.f; s = (float)(kbest[b * T_ + p] + 1); }
        nmask[b * T_ + j] = nm;
        sel[b * T_ + j]   = s;
    }

    // loss finalize: block 0 (partials ready: k_epi/k_scan precede this)
    if (blockIdx.x == 0) {
        __shared__ double rc[256];
        __shared__ double rv[256];
        __shared__ double rs[256];
        const int tid = threadIdx.x;
        double sc = 0.0, sv = 0.0, ssm = 0.0;
        #pragma unroll
        for (int i = 0; i < 4; ++i) {
            sc  += (double)commit_part[tid + 256 * i];
            sv  += (double)valid_part[tid + 256 * i];
            ssm += (double)smooth_part[tid + 256 * i];
        }
        rc[tid] = sc; rv[tid] = sv; rs[tid] = ssm;
        __syncthreads();
        for (int off = 128; off > 0; off >>= 1) {
            if (tid < off) {
                rc[tid] += rc[tid + off];
                rv[tid] += rv[tid + off];
                rs[tid] += rs[tid + off];
            }
            __syncthreads();
        }
        if (tid == 0) {
            double valid = rv[0];
            out[0] = (float)(rs[0] / (valid - (double)B_));  // m1.sum() = valid - B
            out[1] = (float)(rc[0] / valid);
        }
    }
}

extern "C" void kernel_launch(void* const* d_in, const int* in_sizes, int n_in,
                              void* d_out, int out_size, void* d_ws, size_t ws_size,
                              hipStream_t stream) {
    const float* z    = (const float*)d_in[0];
    const float* cb   = (const float*)d_in[1];
    const float* mask = (const float*)d_in[2];
    float* out = (float*)d_out;
    char* ws = (char*)d_ws;

    int*            flagcnt     = (int*)(ws + 0);
    float*          ee          = (float*)(ws + 64);
    unsigned short* Eh          = (unsigned short*)(ws + 4224);
    unsigned short* El          = (unsigned short*)(ws + 135296);
    int*            kbest       = (int*)(ws + 266368);
    int*            selpos      = (int*)(ws + 528512);
    int*            nst         = (int*)(ws + 790656);
    float*          commit_part = (float*)(ws + 791680);
    float*          valid_part  = (float*)(ws + 795776);
    float*          smooth_part = (float*)(ws + 799872);
    int*            flaglist    = (int*)(ws + 804032);
    float*          ee2         = (float*)(ws + 1066176);

    float* zqo   = out + 2;
    float* nzq   = zqo + (size_t)BT_ * C_;
    float* nmask = nzq + (size_t)BT_ * C_;
    float* sel   = nmask + BT_;

    k_prep  <<<16,   64,  0, stream>>>(cb, ee, ee2, Eh, El, flagcnt);
    k_assign<<<256,  512, 0, stream>>>(z, Eh, El, ee2, kbest, flaglist, flagcnt);
    k_fix   <<<1024, 256, 0, stream>>>(z, cb, ee, flagcnt, flaglist, kbest);
    k_epi   <<<1024, 256, 0, stream>>>(z, cb, mask, kbest, zqo,
                                       commit_part, valid_part, smooth_part);
    k_scan  <<<B_,   256, 0, stream>>>(kbest, mask, selpos, nst);
    k_gsel  <<<4096, 256, 0, stream>>>(zqo, kbest, selpos, nst,
                                       commit_part, valid_part, smooth_part,
                                       nzq, nmask, sel, out);
}

// Round 10
// 139.505 us; speedup vs baseline: 1.0817x; 1.0817x over previous
//
#include <hip/hip_runtime.h>
#include <math.h>

typedef __attribute__((ext_vector_type(8))) short short8;
typedef __attribute__((ext_vector_type(4))) float f32x4;

#define B_  16
#define T_  4096
#define C_  64
#define KE_ 1023
#define BT_ (B_ * T_)
// guard in d/2-space: == baseline's 1e-3 in d-space; >= 3x provable bf16-split err
#define WINHALF 5e-4f

// ---------------- ws layout (bytes) ----------------
// [0,       64)      int   flagcnt
// [64,      4160)    float ee[1024]        (|e_k|^2 raw, for k_fix; ee[1023]=+inf)
// [4224,    135296)  u16   Eh[1024*64]     (bf16 hi of NEGATED codebook[1:])
// [135296,  266368)  u16   El[1024*64]     (bf16 lo residual of NEGATED codebook)
// [266368,  528512)  int   kbest[BT]
// [528512,  790656)  int   selpos[BT]
// [790656,  790720)  int   nst[B]
// [791680,  795776)  float commit_part[1024]
// [795776,  799872)  float valid_part[1024]
// [799872,  803968)  float smooth_part[1024]
// [804032,  1066176) int   flaglist[BT]
// [1066176, 1070272) float ee2[1024]       (0.5 + |e_k|^2/2 for C-init; [1023]=+inf)

__device__ __forceinline__ unsigned short f2bf(float x) {
    unsigned int u = __float_as_uint(x);
    unsigned int r = (u + 0x7FFFu + ((u >> 16) & 1u)) >> 16;   // RNE
    return (unsigned short)r;
}
__device__ __forceinline__ float bf2f(unsigned short h) {
    return __uint_as_float(((unsigned int)h) << 16);
}

typedef __attribute__((address_space(1))) const unsigned int g_u32;
typedef __attribute__((address_space(3))) unsigned int l_u32;
__device__ __forceinline__ void gload16(const void* g, void* l) {
    // dest = wave-uniform LDS base + lane*16B; src is per-lane global addr
    __builtin_amdgcn_global_load_lds((g_u32*)g, (l_u32*)l, 16, 0, 0);
}

// ---- prep: ee, ee2, bf16 hi/lo of NEGATED codebook, flagcnt=0 ----
__global__ __launch_bounds__(64) void k_prep(const float* __restrict__ cb,
                                             float* __restrict__ ee,
                                             float* __restrict__ ee2,
                                             unsigned short* __restrict__ Eh,
                                             unsigned short* __restrict__ El,
                                             int* __restrict__ flagcnt) {
    const int k = blockIdx.x * 64 + threadIdx.x;   // 0..1023
    if (k == 0) *flagcnt = 0;
    unsigned int* EhU = (unsigned int*)Eh;
    unsigned int* ElU = (unsigned int*)El;
    if (k < KE_) {
        const float* r = cb + (size_t)(k + 1) * C_;
        float s = 0.f;
        #pragma unroll
        for (int c = 0; c < C_; c += 2) {
            const float x0 = r[c], x1 = r[c + 1];
            s = fmaf(x0, x0, s);
            s = fmaf(x1, x1, s);
            const float n0 = -x0, n1 = -x1;            // negated codebook
            const unsigned short h0 = f2bf(n0), h1 = f2bf(n1);
            const unsigned short l0 = f2bf(n0 - bf2f(h0));
            const unsigned short l1 = f2bf(n1 - bf2f(h1));
            EhU[k * 32 + c / 2] = (unsigned int)h0 | ((unsigned int)h1 << 16);
            ElU[k * 32 + c / 2] = (unsigned int)l0 | ((unsigned int)l1 << 16);
        }
        ee[k]  = s;
        ee2[k] = 0.5f + 0.5f * s;      // acc init => acc_final = d/2
    } else {        // k == 1023 pad: zero rows, inf distance
        #pragma unroll
        for (int c = 0; c < 32; ++c) { EhU[k * 32 + c] = 0u; ElU[k * 32 + c] = 0u; }
        ee[k]  = INFINITY;
        ee2[k] = INFINITY;
    }
}

// ---- hot kernel: R5/R7-verified shape (512 blocks x 4 waves, 32q/wave) ----
__global__ __launch_bounds__(256, 2) void k_assign(
    const float* __restrict__ z, const unsigned short* __restrict__ Eh,
    const unsigned short* __restrict__ El, const float* __restrict__ ee2,
    int* __restrict__ kbest, int* __restrict__ flaglist,
    int* __restrict__ flagcnt) {

    __shared__ __align__(16) unsigned short s_eh[2][128 * 64];
    __shared__ __align__(16) unsigned short s_el[2][128 * 64];
    __shared__ float s_ee[2][128];

    const int tid  = threadIdx.x;
    const int wave = tid >> 6;
    const int lane = tid & 63;
    const int col  = lane & 15;
    const int quad = lane >> 4;
    const int Q0   = blockIdx.x * 128 + wave * 32;

    // ---- A fragments: 32 queries per wave (2 groups of 16), hi/lo ----
    short8 ah[2][2], al[2][2];
    #pragma unroll
    for (int g = 0; g < 2; ++g) {
        const float4* zp = (const float4*)(z + (size_t)(Q0 + g * 16 + col) * C_);
        const float4 f0 = zp[quad * 2];
        const float4 f1 = zp[quad * 2 + 1];
        const float4 f2 = zp[8 + quad * 2];
        const float4 f3 = zp[8 + quad * 2 + 1];
        float xs[16] = {f0.x, f0.y, f0.z, f0.w, f1.x, f1.y, f1.z, f1.w,
                        f2.x, f2.y, f2.z, f2.w, f3.x, f3.y, f3.z, f3.w};
        float ss = 0.f;
        #pragma unroll
        for (int i = 0; i < 16; ++i) ss = fmaf(xs[i], xs[i], ss);
        ss += __shfl_xor(ss, 16);
        ss += __shfl_xor(ss, 32);
        const float inv = 1.f / fmaxf(sqrtf(ss), 1e-12f);
        short8 h0, h1, l0, l1;
        #pragma unroll
        for (int i = 0; i < 8; ++i) {
            const float x = xs[i] * inv;
            const unsigned short hx = f2bf(x);
            h0[i] = (short)hx;
            l0[i] = (short)f2bf(x - bf2f(hx));
            const float y = xs[8 + i] * inv;
            const unsigned short hy = f2bf(y);
            h1[i] = (short)hy;
            l1[i] = (short)f2bf(y - bf2f(hy));
        }
        ah[g][0] = h0; ah[g][1] = h1;
        al[g][0] = l0; al[g][1] = l1;
    }

    // exact fp32 top-2 (value + index) in d/2-space
    float bestv[2][4], secv[2][4];
    int   bkk[2][4];
    #pragma unroll
    for (int g = 0; g < 2; ++g)
        #pragma unroll
        for (int r = 0; r < 4; ++r) {
            bestv[g][r] = INFINITY; secv[g][r] = INFINITY; bkk[g][r] = 0;
        }

    // staging geometry (256 threads, verified R1/R2): round j covers 32 rows.
    const int srow = tid >> 3;                    // 0..31 (row within round)
    const int schk = (tid & 7) ^ (srow & 7);      // pre-swizzled source chunk
    const int ldsb = (wave * 8) * 64;             // wave-uniform LDS base (shorts)

#define STAGE_J(tt, bb, j) do {                                                \
        const size_t go = (size_t)((tt) * 128 + (j) * 32 + srow) * 64          \
                          + (size_t)schk * 8;                                  \
        gload16(Eh + go, (void*)&s_eh[bb][ldsb + (j) * 2048]);                 \
        gload16(El + go, (void*)&s_el[bb][ldsb + (j) * 2048]);                 \
    } while (0)

    int cur = 0;
    #pragma unroll
    for (int j = 0; j < 4; ++j) STAGE_J(0, 0, j);
    if (tid < 128) s_ee[0][tid] = ee2[tid];
    __syncthreads();                 // drains vmcnt(0): tile 0 resident

    const int coff = (quad ^ (col & 7)) * 8;      // swizzled read chunk (shorts)

    for (int t = 0; t < 8; ++t) {
        // first half of next-tile staging: issue immediately after barrier
        if (t < 7) { STAGE_J(t + 1, cur ^ 1, 0); STAGE_J(t + 1, cur ^ 1, 1); }

        float ev[8];
        #pragma unroll
        for (int s = 0; s < 8; ++s) ev[s] = s_ee[cur][s * 16 + col];

        // preload s=0 B-fragments into registers
        short8 fh0 = *(const short8*)&s_eh[cur][col * 64 + coff];
        short8 fh1 = *(const short8*)&s_eh[cur][col * 64 + (coff ^ 32)];
        short8 fl0 = *(const short8*)&s_el[cur][col * 64 + coff];
        short8 fl1 = *(const short8*)&s_el[cur][col * 64 + (coff ^ 32)];

        // second half of next-tile staging (spread: no post-barrier burst)
        if (t < 7) {
            STAGE_J(t + 1, cur ^ 1, 2); STAGE_J(t + 1, cur ^ 1, 3);
            if (tid < 128) s_ee[cur ^ 1][tid] = ee2[(t + 1) * 128 + tid];
        }

        const int kb = t * 128 + col;

        #pragma unroll
        for (int s = 0; s < 8; ++s) {
            // prefetch s+1 fragments (redundant reload of s=7 on last step)
            const int sn = (s < 7) ? (s + 1) : 7;
            const int rb = (sn * 16 + col) * 64;
            short8 nh0 = *(const short8*)&s_eh[cur][rb + coff];
            short8 nh1 = *(const short8*)&s_eh[cur][rb + (coff ^ 32)];
            short8 nl0 = *(const short8*)&s_el[cur][rb + coff];
            short8 nl1 = *(const short8*)&s_el[cur][rb + (coff ^ 32)];

            const float e2 = ev[s];
            f32x4 p0 = {e2, e2, e2, e2};
            f32x4 p1 = {e2, e2, e2, e2};
            __builtin_amdgcn_s_setprio(1);
            // two independent 6-chains, interleaved for MFMA-pipe overlap
            p0 = __builtin_amdgcn_mfma_f32_16x16x32_bf16(ah[0][0], fh0, p0, 0, 0, 0);
            p1 = __builtin_amdgcn_mfma_f32_16x16x32_bf16(ah[1][0], fh0, p1, 0, 0, 0);
            p0 = __builtin_amdgcn_mfma_f32_16x16x32_bf16(ah[0][1], fh1, p0, 0, 0, 0);
            p1 = __builtin_amdgcn_mfma_f32_16x16x32_bf16(ah[1][1], fh1, p1, 0, 0, 0);
            p0 = __builtin_amdgcn_mfma_f32_16x16x32_bf16(ah[0][0], fl0, p0, 0, 0, 0);
            p1 = __builtin_amdgcn_mfma_f32_16x16x32_bf16(ah[1][0], fl0, p1, 0, 0, 0);
            p0 = __builtin_amdgcn_mfma_f32_16x16x32_bf16(ah[0][1], fl1, p0, 0, 0, 0);
            p1 = __builtin_amdgcn_mfma_f32_16x16x32_bf16(ah[1][1], fl1, p1, 0, 0, 0);
            p0 = __builtin_amdgcn_mfma_f32_16x16x32_bf16(al[0][0], fh0, p0, 0, 0, 0);
            p1 = __builtin_amdgcn_mfma_f32_16x16x32_bf16(al[1][0], fh0, p1, 0, 0, 0);
            p0 = __builtin_amdgcn_mfma_f32_16x16x32_bf16(al[0][1], fh1, p0, 0, 0, 0);
            p1 = __builtin_amdgcn_mfma_f32_16x16x32_bf16(al[1][1], fh1, p1, 0, 0, 0);
            __builtin_amdgcn_s_setprio(0);

            const int kc = kb + s * 16;
            #pragma unroll
            for (int r = 0; r < 4; ++r) {
                {
                    const float v  = p0[r];       // = d/2 exactly (fp32)
                    const float bo = bestv[0][r];
                    bkk[0][r]   = (v < bo) ? kc : bkk[0][r];
                    secv[0][r]  = fminf(secv[0][r], fmaxf(bo, v));
                    bestv[0][r] = fminf(bo, v);
                }
                {
                    const float v  = p1[r];
                    const float bo = bestv[1][r];
                    bkk[1][r]   = (v < bo) ? kc : bkk[1][r];
                    secv[1][r]  = fminf(secv[1][r], fmaxf(bo, v));
                    bestv[1][r] = fminf(bo, v);
                }
            }
            fh0 = nh0; fh1 = nh1; fl0 = nl0; fl1 = nl1;
        }
        __syncthreads();             // reads done + next-tile stage drained
        cur ^= 1;
    }
#undef STAGE_J

    #pragma unroll
    for (int g = 0; g < 2; ++g) {
        #pragma unroll
        for (int r = 0; r < 4; ++r) {
            float b  = bestv[g][r], sc = secv[g][r];
            int   k  = bkk[g][r];
            #pragma unroll
            for (int off = 1; off < 16; off <<= 1) {
                const float ob = __shfl_xor(b, off);
                const int   ok = __shfl_xor(k, off);
                const float os = __shfl_xor(sc, off);
                const bool take = (ob < b) || (ob == b && ok < k);
                const float lose = take ? b : ob;
                sc = fminf(fminf(sc, os), lose);
                b  = take ? ob : b;
                k  = take ? ok : k;
            }
            if (col == 0) {
                const int q = Q0 + g * 16 + quad * 4 + r;
                kbest[q] = k;
                if (!(sc - b > WINHALF)) {              // ambiguous -> exact path
                    const int pos = atomicAdd(flagcnt, 1);
                    flaglist[pos] = q;
                }
            }
        }
    }
}

// ---- exact fp32 rescan, BLOCK per flagged query (verified, unchanged) ----
__global__ __launch_bounds__(256) void k_fix(const float* __restrict__ z,
                                             const float* __restrict__ cb,
                                             const float* __restrict__ ee,
                                             const int* __restrict__ flagcnt,
                                             const int* __restrict__ flaglist,
                                             int* __restrict__ kbest) {
    __shared__ float s_z[64];
    __shared__ float s_bv[4];
    __shared__ int   s_bk[4];
    const int tid  = threadIdx.x;
    const int lane = tid & 63;
    const int wave = tid >> 6;
    const int n = *flagcnt;

    for (int i = blockIdx.x; i < n; i += 1024) {
        const int q = flaglist[i];
        __syncthreads();               // s_z reuse guard across iterations
        if (tid < 16) ((float4*)s_z)[tid] = ((const float4*)(z + (size_t)q * C_))[tid];
        __syncthreads();

        float4 zn[16];
        float ss = 0.f;
        #pragma unroll
        for (int c4 = 0; c4 < 16; ++c4) {
            const float4 v = ((const float4*)s_z)[c4];
            zn[c4] = v;
            ss = fmaf(v.x, v.x, ss); ss = fmaf(v.y, v.y, ss);
            ss = fmaf(v.z, v.z, ss); ss = fmaf(v.w, v.w, ss);
        }
        const float nrm = fmaxf(sqrtf(ss), 1e-12f);
        #pragma unroll
        for (int c4 = 0; c4 < 16; ++c4) {
            zn[c4].x /= nrm; zn[c4].y /= nrm; zn[c4].z /= nrm; zn[c4].w /= nrm;
        }

        const int k0 = tid * 4;        // codes k0..k0+3 (k0+3 <= 1023)
        const float4* e0 = (const float4*)(cb + (size_t)(k0 + 1) * C_);
        const float4* e1 = (const float4*)(cb + (size_t)(k0 + 2) * C_);
        const float4* e2 = (const float4*)(cb + (size_t)(k0 + 3) * C_);
        const float4* e3 = (const float4*)(cb + (size_t)((k0 + 4 <= KE_) ? (k0 + 4) : KE_) * C_);
        float d0 = 0.f, d1 = 0.f, d2 = 0.f, d3 = 0.f;
        #pragma unroll
        for (int c4 = 0; c4 < 16; ++c4) {   // in-order fp32 chains
            const float4 x = zn[c4];
            const float4 a = e0[c4], b = e1[c4], c = e2[c4], d = e3[c4];
            d0 = fmaf(x.x, a.x, d0); d0 = fmaf(x.y, a.y, d0);
            d0 = fmaf(x.z, a.z, d0); d0 = fmaf(x.w, a.w, d0);
            d1 = fmaf(x.x, b.x, d1); d1 = fmaf(x.y, b.y, d1);
            d1 = fmaf(x.z, b.z, d1); d1 = fmaf(x.w, b.w, d1);
            d2 = fmaf(x.x, c.x, d2); d2 = fmaf(x.y, c.y, d2);
            d2 = fmaf(x.z, c.z, d2); d2 = fmaf(x.w, c.w, d2);
            d3 = fmaf(x.x, d.x, d3); d3 = fmaf(x.y, d.y, d3);
            d3 = fmaf(x.z, d.z, d3); d3 = fmaf(x.w, d.w, d3);
        }
        float bv = INFINITY;
        int   bk = 0;
        float v;
        v = fmaf(-2.f, d0, ee[k0 + 0]); if (v < bv) { bv = v; bk = k0 + 0; }
        v = fmaf(-2.f, d1, ee[k0 + 1]); if (v < bv) { bv = v; bk = k0 + 1; }
        v = fmaf(-2.f, d2, ee[k0 + 2]); if (v < bv) { bv = v; bk = k0 + 2; }
        v = fmaf(-2.f, d3, ee[k0 + 3]); if (v < bv) { bv = v; bk = k0 + 3; }

        #pragma unroll
        for (int off = 32; off > 0; off >>= 1) {
            const float ov = __shfl_down(bv, off);
            const int   ok = __shfl_down(bk, off);
            if (ov < bv || (ov == bv && ok < bk)) { bv = ov; bk = ok; }
        }
        if (lane == 0) { s_bv[wave] = bv; s_bk[wave] = bk; }
        __syncthreads();
        if (tid == 0) {
            float fb = s_bv[0]; int fk = s_bk[0];
            #pragma unroll
            for (int w = 1; w < 4; ++w) {
                if (s_bv[w] < fb || (s_bv[w] == fb && s_bk[w] < fk)) {
                    fb = s_bv[w]; fk = s_bk[w];
                }
            }
            kbest[q] = fk;
        }
    }
}

// ---- FUSED epilogue + compaction: blocks 0..15 = scan, 16..1039 = epi ----
// Scan and epi both depend only on post-fix kbest (+ z/cb/mask); no cross
// dependency, so they share one launch. Scan blocks dispatched FIRST so the
// 16-block latency-bound path overlaps epi's 1024 blocks instead of running
// serially after them (R8 post-mortem: scan serial cost ~6-10 us).
__global__ __launch_bounds__(256) void k_episcan(
    const float* __restrict__ z, const float* __restrict__ cb,
    const float* __restrict__ mask, const int* __restrict__ kbest,
    float* __restrict__ zqo,
    float* __restrict__ commit_part, float* __restrict__ valid_part,
    float* __restrict__ smooth_part,
    int* __restrict__ selpos, int* __restrict__ nst) {

    const int tid = threadIdx.x;

    if (blockIdx.x < 16) {
        // ---------------- scan path (verified R7 k_scan, verbatim) --------
        __shared__ int cnt[256];
        const int b = blockIdx.x;
        const int base = b * T_;
        const int t0 = tid * 16;

        int flags = 0, c = 0;
        int prev = (tid == 0) ? -1 : kbest[base + t0 - 1];
        #pragma unroll
        for (int i = 0; i < 16; ++i) {
            const int t = t0 + i;
            const int cur = kbest[base + t];
            const int is = (t == 0) ? 1
                         : ((cur != prev && mask[base + t] > 0.f) ? 1 : 0);
            flags |= is << i;
            c += is;
            prev = cur;
        }
        cnt[tid] = c;
        __syncthreads();
        for (int off = 1; off < 256; off <<= 1) {
            int add = (tid >= off) ? cnt[tid - off] : 0;
            __syncthreads();
            cnt[tid] += add;
            __syncthreads();
        }
        int pos = cnt[tid] - c;   // exclusive prefix
        #pragma unroll
        for (int i = 0; i < 16; ++i) {
            if ((flags >> i) & 1) selpos[base + pos++] = t0 + i;
        }
        if (tid == 255) nst[b] = cnt[255];
        return;
    }

    // ---------------- epi path (verified R7 k_epi, bid-shifted) -----------
    __shared__ float s_red[12];
    const int bid  = blockIdx.x - 16;
    const int lane = tid & 63;
    const int wave = tid >> 6;
    const int gt   = bid * 256 + tid;
    const int q    = gt >> 2;          // query index
    const int p    = gt & 3;           // 16-column chunk within query
    const int grp  = lane >> 2;        // 0..15 query-group within wave

    const int bi = kbest[q];
    const float m = mask[q];

    const float4* zp = (const float4*)(z + (size_t)q * C_ + p * 16);
    const float4* er = (const float4*)(cb + (size_t)(bi + 1) * C_ + p * 16);
    float4* zo = (float4*)(zqo + (size_t)q * C_ + p * 16);

    float4 zr[4];
    float ss = 0.f;
    #pragma unroll
    for (int i = 0; i < 4; ++i) {
        float4 v = zp[i];
        zr[i] = v;
        ss = fmaf(v.x, v.x, ss); ss = fmaf(v.y, v.y, ss);
        ss = fmaf(v.z, v.z, ss); ss = fmaf(v.w, v.w, ss);
    }
    // norm over the 4-lane group owning this query
    ss += __shfl_xor(ss, 1);
    ss += __shfl_xor(ss, 2);
    const float nrm = fmaxf(sqrtf(ss), 1e-12f);

    float commit = 0.f, sm = 0.f;
    float4 ov[4];
    #pragma unroll
    for (int c4 = 0; c4 < 4; ++c4) {
        const float z0 = zr[c4].x / nrm, z1 = zr[c4].y / nrm;
        const float z2 = zr[c4].z / nrm, z3 = zr[c4].w / nrm;
        const float4 e4 = er[c4];
        const float q0 = e4.x * m, q1 = e4.y * m, q2 = e4.z * m, q3 = e4.w * m;
        float4 o;
        o.x = (z0 + q0) - z0;              // straight-through forward value
        o.y = (z1 + q1) - z1;
        o.z = (z2 + q2) - z2;
        o.w = (z3 + q3) - z3;
        zo[c4] = o;
        ov[c4] = o;
        const float d0 = z0 - q0, d1 = z1 - q1, d2 = z2 - q2, d3 = z3 - q3;
        commit = fmaf(d0, d0, commit); commit = fmaf(d1, d1, commit);
        commit = fmaf(d2, d2, commit); commit = fmaf(d3, d3, commit);
    }
    commit *= m;

    // within-wave pairs (groups 0..14); shfl OOB returns own value -> diff 0
    float mnext = 0.f;
    if (grp != 15) mnext = mask[q + 1];    // q+1 in-range (grp 15 excluded)
    #pragma unroll
    for (int c4 = 0; c4 < 4; ++c4) {
        const float n0 = __shfl_down(ov[c4].x, 4);
        const float n1 = __shfl_down(ov[c4].y, 4);
        const float n2 = __shfl_down(ov[c4].z, 4);
        const float n3 = __shfl_down(ov[c4].w, 4);
        const float x0 = ov[c4].x - n0, x1 = ov[c4].y - n1;
        const float x2 = ov[c4].z - n2, x3 = ov[c4].w - n3;
        sm = fmaf(x0, x0, sm); sm = fmaf(x1, x1, sm);
        sm = fmaf(x2, x2, sm); sm = fmaf(x3, x3, sm);
    }
    sm *= mnext;

    // boundary pair (q, q+1) for group 15: recompute o(q+1) locally.
    if (grp == 15) {
        float mn = 0.f;
        if ((q & (T_ - 1)) != T_ - 1) mn = mask[q + 1];   // also guards q+1 OOB
        if (mn > 0.f) {
            const int bi2 = kbest[q + 1];
            const float4* zp2 = (const float4*)(z + (size_t)(q + 1) * C_ + p * 16);
            const float4* er2 = (const float4*)(cb + (size_t)(bi2 + 1) * C_ + p * 16);
            float4 zr2[4];
            float s2 = 0.f;
            #pragma unroll
            for (int i = 0; i < 4; ++i) {
                float4 v = zp2[i];
                zr2[i] = v;
                s2 = fmaf(v.x, v.x, s2); s2 = fmaf(v.y, v.y, s2);
                s2 = fmaf(v.z, v.z, s2); s2 = fmaf(v.w, v.w, s2);
            }
            s2 += __shfl_xor(s2, 1);
            s2 += __shfl_xor(s2, 2);
            const float nrm2 = fmaxf(sqrtf(s2), 1e-12f);
            float smb = 0.f;
            #pragma unroll
            for (int c4 = 0; c4 < 4; ++c4) {
                const float w0 = zr2[c4].x / nrm2, w1 = zr2[c4].y / nrm2;
                const float w2 = zr2[c4].z / nrm2, w3 = zr2[c4].w / nrm2;
                const float4 e4 = er2[c4];
                const float a0 = e4.x * mn, a1 = e4.y * mn;
                const float a2 = e4.z * mn, a3 = e4.w * mn;
                const float o0 = (w0 + a0) - w0;   // bitwise == zqo[q+1] chunk
                const float o1 = (w1 + a1) - w1;
                const float o2 = (w2 + a2) - w2;
                const float o3 = (w3 + a3) - w3;
                const float x0 = ov[c4].x - o0, x1 = ov[c4].y - o1;
                const float x2 = ov[c4].z - o2, x3 = ov[c4].w - o3;
                smb = fmaf(x0, x0, smb); smb = fmaf(x1, x1, smb);
                smb = fmaf(x2, x2, smb); smb = fmaf(x3, x3, smb);
            }
            sm = smb * mn;
        }
    }

    float vc = (p == 0) ? m : 0.f;     // count each query once
    #pragma unroll
    for (int off = 32; off > 0; off >>= 1) {
        commit += __shfl_down(commit, off);
        vc     += __shfl_down(vc, off);
        sm     += __shfl_down(sm, off);
    }
    if (lane == 0) { s_red[wave] = commit; s_red[4 + wave] = vc; s_red[8 + wave] = sm; }
    __syncthreads();
    if (tid == 0) {
        commit_part[bid] = s_red[0] + s_red[1] + s_red[2] + s_red[3];
        valid_part[bid]  = s_red[4] + s_red[5] + s_red[6] + s_red[7];
        smooth_part[bid] = s_red[8] + s_red[9] + s_red[10] + s_red[11];
    }
}

// ---- fused n_z_q gather + n_mask + selected_encodings + loss finalize ----
__global__ __launch_bounds__(256) void k_gsel(const float* __restrict__ zqo,
                                              const int* __restrict__ kbest,
                                              const int* __restrict__ selpos,
                                              const int* __restrict__ nst,
                                              const float* __restrict__ commit_part,
                                              const float* __restrict__ valid_part,
                                              const float* __restrict__ smooth_part,
                                              float* __restrict__ nzq,
                                              float* __restrict__ nmask,
                                              float* __restrict__ sel,
                                              float* __restrict__ out) {
    const int gid = blockIdx.x * 256 + threadIdx.x;   // float4 index
    const int b   = gid >> 16;          // T*C/4 = 65536 float4 per batch
    const int rem = gid & 65535;
    const int j   = rem >> 4;
    const int c4  = rem & 15;
    const int n   = nst[b];
    float4 v = make_float4(0.f, 0.f, 0.f, 0.f);
    int p = 0;
    if (j < n) {
        p = selpos[b * T_ + j];
        v = ((const float4*)zqo)[((size_t)b * T_ + p) * 16 + c4];
    }
    ((float4*)nzq)[gid] = v;
    if (c4 == 0) {
        float nm = 0.f, s = 0.f;
        if (j < n) { nm = 1.f; s = (float)(kbest[b * T_ + p] + 1); }
        nmask[b * T_ + j] = nm;
        sel[b * T_ + j]   = s;
    }

    // loss finalize: block 0 (partials ready: k_episcan precedes this)
    if (blockIdx.x == 0) {
        __shared__ double rc[256];
        __shared__ double rv[256];
        __shared__ double rs[256];
        const int tid = threadIdx.x;
        double sc = 0.0, sv = 0.0, ssm = 0.0;
        #pragma unroll
        for (int i = 0; i < 4; ++i) {
            sc  += (double)commit_part[tid + 256 * i];
            sv  += (double)valid_part[tid + 256 * i];
            ssm += (double)smooth_part[tid + 256 * i];
        }
        rc[tid] = sc; rv[tid] = sv; rs[tid] = ssm;
        __syncthreads();
        for (int off = 128; off > 0; off >>= 1) {
            if (tid < off) {
                rc[tid] += rc[tid + off];
                rv[tid] += rv[tid + off];
                rs[tid] += rs[tid + off];
            }
            __syncthreads();
        }
        if (tid == 0) {
            double valid = rv[0];
            out[0] = (float)(rs[0] / (valid - (double)B_));  // m1.sum() = valid - B
            out[1] = (float)(rc[0] / valid);
        }
    }
}

extern "C" void kernel_launch(void* const* d_in, const int* in_sizes, int n_in,
                              void* d_out, int out_size, void* d_ws, size_t ws_size,
                              hipStream_t stream) {
    const float* z    = (const float*)d_in[0];
    const float* cb   = (const float*)d_in[1];
    const float* mask = (const float*)d_in[2];
    float* out = (float*)d_out;
    char* ws = (char*)d_ws;

    int*            flagcnt     = (int*)(ws + 0);
    float*          ee          = (float*)(ws + 64);
    unsigned short* Eh          = (unsigned short*)(ws + 4224);
    unsigned short* El          = (unsigned short*)(ws + 135296);
    int*            kbest       = (int*)(ws + 266368);
    int*            selpos      = (int*)(ws + 528512);
    int*            nst         = (int*)(ws + 790656);
    float*          commit_part = (float*)(ws + 791680);
    float*          valid_part  = (float*)(ws + 795776);
    float*          smooth_part = (float*)(ws + 799872);
    int*            flaglist    = (int*)(ws + 804032);
    float*          ee2         = (float*)(ws + 1066176);

    float* zqo   = out + 2;
    float* nzq   = zqo + (size_t)BT_ * C_;
    float* nmask = nzq + (size_t)BT_ * C_;
    float* sel   = nmask + BT_;

    k_prep   <<<16,   64,  0, stream>>>(cb, ee, ee2, Eh, El, flagcnt);
    k_assign <<<512,  256, 0, stream>>>(z, Eh, El, ee2, kbest, flaglist, flagcnt);
    k_fix    <<<1024, 256, 0, stream>>>(z, cb, ee, flagcnt, flaglist, kbest);
    k_episcan<<<1040, 256, 0, stream>>>(z, cb, mask, kbest, zqo,
                                        commit_part, valid_part, smooth_part,
                                        selpos, nst);
    k_gsel   <<<4096, 256, 0, stream>>>(zqo, kbest, selpos, nst,
                                        commit_part, valid_part, smooth_part,
                                        nzq, nmask, sel, out);
}

// Round 11
// 138.942 us; speedup vs baseline: 1.0861x; 1.0041x over previous
//
#include <hip/hip_runtime.h>
#include <math.h>

typedef __attribute__((ext_vector_type(8))) short short8;
typedef __attribute__((ext_vector_type(4))) float f32x4;

#define B_  16
#define T_  4096
#define C_  64
#define KE_ 1023
#define BT_ (B_ * T_)
// guard in d/2-space: == baseline's 1e-3 in d-space; >= 3x provable bf16-split err
#define WINHALF 5e-4f

// ---------------- ws layout (bytes) ----------------
// [0,       64)      int   flagcnt
// [64,      4160)    float ee[1024]        (|e_k|^2 raw, for k_fix; ee[1023]=+inf)
// [4224,    135296)  u16   Eh[1024*64]     (bf16 hi of NEGATED codebook[1:])
// [135296,  266368)  u16   El[1024*64]     (bf16 lo residual of NEGATED codebook)
// [266368,  528512)  int   kbest[BT]
// [528512,  790656)  int   selpos[BT]
// [790656,  790720)  int   nst[B]
// [791680,  795776)  float commit_part[1024]
// [795776,  799872)  float valid_part[1024]
// [799872,  803968)  float smooth_part[1024]
// [804032,  1066176) int   flaglist[BT]
// [1066176, 1070272) float ee2[1024]       (0.5 + |e_k|^2/2 for C-init; [1023]=+inf)

__device__ __forceinline__ unsigned short f2bf(float x) {
    unsigned int u = __float_as_uint(x);
    unsigned int r = (u + 0x7FFFu + ((u >> 16) & 1u)) >> 16;   // RNE
    return (unsigned short)r;
}
__device__ __forceinline__ float bf2f(unsigned short h) {
    return __uint_as_float(((unsigned int)h) << 16);
}

typedef __attribute__((address_space(1))) const unsigned int g_u32;
typedef __attribute__((address_space(3))) unsigned int l_u32;
__device__ __forceinline__ void gload16(const void* g, void* l) {
    // dest = wave-uniform LDS base + lane*16B; src is per-lane global addr
    __builtin_amdgcn_global_load_lds((g_u32*)g, (l_u32*)l, 16, 0, 0);
}

// ---- prep: R11 reshape -- 128 blocks x 256 threads, one u32 chunk/thread ----
// Conversion writes (Eh/El) are bitwise-identical to the old serial loop and
// perfectly coalesced. ee/ee2 computed by the c==0 lane in the EXACT original
// serial fmaf order (bitwise-identical ee -> k_fix tie decisions unchanged).
__global__ __launch_bounds__(256) void k_prep(const float* __restrict__ cb,
                                              float* __restrict__ ee,
                                              float* __restrict__ ee2,
                                              unsigned short* __restrict__ Eh,
                                              unsigned short* __restrict__ El,
                                              int* __restrict__ flagcnt) {
    const int gid = blockIdx.x * 256 + threadIdx.x;   // 0..32767
    const int k = gid >> 5;          // code 0..1023
    const int c = gid & 31;          // u32 chunk (cols 2c, 2c+1)
    if (gid == 0) *flagcnt = 0;
    unsigned int* EhU = (unsigned int*)Eh;
    unsigned int* ElU = (unsigned int*)El;
    if (k < KE_) {
        const float x0 = cb[(size_t)(k + 1) * C_ + 2 * c];
        const float x1 = cb[(size_t)(k + 1) * C_ + 2 * c + 1];
        const float n0 = -x0, n1 = -x1;            // negated codebook
        const unsigned short h0 = f2bf(n0), h1 = f2bf(n1);
        const unsigned short l0 = f2bf(n0 - bf2f(h0));
        const unsigned short l1 = f2bf(n1 - bf2f(h1));
        EhU[k * 32 + c] = (unsigned int)h0 | ((unsigned int)h1 << 16);
        ElU[k * 32 + c] = (unsigned int)l0 | ((unsigned int)l1 << 16);
        if (c == 0) {   // serial fmaf order == original k_prep (bitwise ee)
            const float* r = cb + (size_t)(k + 1) * C_;
            float s = 0.f;
            #pragma unroll
            for (int cc = 0; cc < C_; cc += 2) {
                const float y0 = r[cc], y1 = r[cc + 1];
                s = fmaf(y0, y0, s);
                s = fmaf(y1, y1, s);
            }
            ee[k]  = s;
            ee2[k] = 0.5f + 0.5f * s;  // acc init => acc_final = d/2
        }
    } else {        // k == 1023 pad: zero rows, inf distance
        EhU[k * 32 + c] = 0u;
        ElU[k * 32 + c] = 0u;
        if (c == 0) { ee[k] = INFINITY; ee2[k] = INFINITY; }
    }
}

// ---- hot kernel: R5/R7 shape; R11 = 4 accumulator chains (3-deep each) ----
// Splitting each group's 6-deep MFMA chain into two 3-deep chains (merged by
// one add) halves the per-s-step serial MFMA latency; 4 chains round-robin
// give the SIMD issue slots between dependent ops. Rounding-order shift is
// ~1e-7, far under WINHALF=5e-4 (unflagged gaps can't flip; flagged -> k_fix).
__global__ __launch_bounds__(256, 2) void k_assign(
    const float* __restrict__ z, const unsigned short* __restrict__ Eh,
    const unsigned short* __restrict__ El, const float* __restrict__ ee2,
    int* __restrict__ kbest, int* __restrict__ flaglist,
    int* __restrict__ flagcnt) {

    __shared__ __align__(16) unsigned short s_eh[2][128 * 64];
    __shared__ __align__(16) unsigned short s_el[2][128 * 64];
    __shared__ float s_ee[2][128];

    const int tid  = threadIdx.x;
    const int wave = tid >> 6;
    const int lane = tid & 63;
    const int col  = lane & 15;
    const int quad = lane >> 4;
    const int Q0   = blockIdx.x * 128 + wave * 32;

    // ---- A fragments: 32 queries per wave (2 groups of 16), hi/lo ----
    short8 ah[2][2], al[2][2];
    #pragma unroll
    for (int g = 0; g < 2; ++g) {
        const float4* zp = (const float4*)(z + (size_t)(Q0 + g * 16 + col) * C_);
        const float4 f0 = zp[quad * 2];
        const float4 f1 = zp[quad * 2 + 1];
        const float4 f2 = zp[8 + quad * 2];
        const float4 f3 = zp[8 + quad * 2 + 1];
        float xs[16] = {f0.x, f0.y, f0.z, f0.w, f1.x, f1.y, f1.z, f1.w,
                        f2.x, f2.y, f2.z, f2.w, f3.x, f3.y, f3.z, f3.w};
        float ss = 0.f;
        #pragma unroll
        for (int i = 0; i < 16; ++i) ss = fmaf(xs[i], xs[i], ss);
        ss += __shfl_xor(ss, 16);
        ss += __shfl_xor(ss, 32);
        const float inv = 1.f / fmaxf(sqrtf(ss), 1e-12f);
        short8 h0, h1, l0, l1;
        #pragma unroll
        for (int i = 0; i < 8; ++i) {
            const float x = xs[i] * inv;
            const unsigned short hx = f2bf(x);
            h0[i] = (short)hx;
            l0[i] = (short)f2bf(x - bf2f(hx));
            const float y = xs[8 + i] * inv;
            const unsigned short hy = f2bf(y);
            h1[i] = (short)hy;
            l1[i] = (short)f2bf(y - bf2f(hy));
        }
        ah[g][0] = h0; ah[g][1] = h1;
        al[g][0] = l0; al[g][1] = l1;
    }

    // exact fp32 top-2 (value + index) in d/2-space
    float bestv[2][4], secv[2][4];
    int   bkk[2][4];
    #pragma unroll
    for (int g = 0; g < 2; ++g)
        #pragma unroll
        for (int r = 0; r < 4; ++r) {
            bestv[g][r] = INFINITY; secv[g][r] = INFINITY; bkk[g][r] = 0;
        }

    // staging geometry (256 threads, verified R1/R2): round j covers 32 rows.
    const int srow = tid >> 3;                    // 0..31 (row within round)
    const int schk = (tid & 7) ^ (srow & 7);      // pre-swizzled source chunk
    const int ldsb = (wave * 8) * 64;             // wave-uniform LDS base (shorts)

#define STAGE_J(tt, bb, j) do {                                                \
        const size_t go = (size_t)((tt) * 128 + (j) * 32 + srow) * 64          \
                          + (size_t)schk * 8;                                  \
        gload16(Eh + go, (void*)&s_eh[bb][ldsb + (j) * 2048]);                 \
        gload16(El + go, (void*)&s_el[bb][ldsb + (j) * 2048]);                 \
    } while (0)

    int cur = 0;
    #pragma unroll
    for (int j = 0; j < 4; ++j) STAGE_J(0, 0, j);
    if (tid < 128) s_ee[0][tid] = ee2[tid];
    __syncthreads();                 // drains vmcnt(0): tile 0 resident

    const int coff = (quad ^ (col & 7)) * 8;      // swizzled read chunk (shorts)

    for (int t = 0; t < 8; ++t) {
        // first half of next-tile staging: issue immediately after barrier
        if (t < 7) { STAGE_J(t + 1, cur ^ 1, 0); STAGE_J(t + 1, cur ^ 1, 1); }

        float ev[8];
        #pragma unroll
        for (int s = 0; s < 8; ++s) ev[s] = s_ee[cur][s * 16 + col];

        // preload s=0 B-fragments into registers
        short8 fh0 = *(const short8*)&s_eh[cur][col * 64 + coff];
        short8 fh1 = *(const short8*)&s_eh[cur][col * 64 + (coff ^ 32)];
        short8 fl0 = *(const short8*)&s_el[cur][col * 64 + coff];
        short8 fl1 = *(const short8*)&s_el[cur][col * 64 + (coff ^ 32)];

        // second half of next-tile staging (spread: no post-barrier burst)
        if (t < 7) {
            STAGE_J(t + 1, cur ^ 1, 2); STAGE_J(t + 1, cur ^ 1, 3);
            if (tid < 128) s_ee[cur ^ 1][tid] = ee2[(t + 1) * 128 + tid];
        }

        const int kb = t * 128 + col;

        #pragma unroll
        for (int s = 0; s < 8; ++s) {
            // prefetch s+1 fragments (redundant reload of s=7 on last step)
            const int sn = (s < 7) ? (s + 1) : 7;
            const int rb = (sn * 16 + col) * 64;
            short8 nh0 = *(const short8*)&s_eh[cur][rb + coff];
            short8 nh1 = *(const short8*)&s_eh[cur][rb + (coff ^ 32)];
            short8 nl0 = *(const short8*)&s_el[cur][rb + coff];
            short8 nl1 = *(const short8*)&s_el[cur][rb + (coff ^ 32)];

            const float e2 = ev[s];
            f32x4 p0a = {e2, e2, e2, e2}, p0b = {0.f, 0.f, 0.f, 0.f};
            f32x4 p1a = {e2, e2, e2, e2}, p1b = {0.f, 0.f, 0.f, 0.f};
            __builtin_amdgcn_s_setprio(1);
            // four 3-deep chains, round-robin interleave (halved chain latency)
            p0a = __builtin_amdgcn_mfma_f32_16x16x32_bf16(ah[0][0], fh0, p0a, 0, 0, 0);
            p1a = __builtin_amdgcn_mfma_f32_16x16x32_bf16(ah[1][0], fh0, p1a, 0, 0, 0);
            p0b = __builtin_amdgcn_mfma_f32_16x16x32_bf16(ah[0][1], fl1, p0b, 0, 0, 0);
            p1b = __builtin_amdgcn_mfma_f32_16x16x32_bf16(ah[1][1], fl1, p1b, 0, 0, 0);
            p0a = __builtin_amdgcn_mfma_f32_16x16x32_bf16(ah[0][1], fh1, p0a, 0, 0, 0);
            p1a = __builtin_amdgcn_mfma_f32_16x16x32_bf16(ah[1][1], fh1, p1a, 0, 0, 0);
            p0b = __builtin_amdgcn_mfma_f32_16x16x32_bf16(al[0][0], fh0, p0b, 0, 0, 0);
            p1b = __builtin_amdgcn_mfma_f32_16x16x32_bf16(al[1][0], fh0, p1b, 0, 0, 0);
            p0a = __builtin_amdgcn_mfma_f32_16x16x32_bf16(ah[0][0], fl0, p0a, 0, 0, 0);
            p1a = __builtin_amdgcn_mfma_f32_16x16x32_bf16(ah[1][0], fl0, p1a, 0, 0, 0);
            p0b = __builtin_amdgcn_mfma_f32_16x16x32_bf16(al[0][1], fh1, p0b, 0, 0, 0);
            p1b = __builtin_amdgcn_mfma_f32_16x16x32_bf16(al[1][1], fh1, p1b, 0, 0, 0);
            __builtin_amdgcn_s_setprio(0);

            const int kc = kb + s * 16;
            #pragma unroll
            for (int r = 0; r < 4; ++r) {
                {
                    const float v  = p0a[r] + p0b[r];   // = d/2 (fp32)
                    const float bo = bestv[0][r];
                    bkk[0][r]   = (v < bo) ? kc : bkk[0][r];
                    secv[0][r]  = fminf(secv[0][r], fmaxf(bo, v));
                    bestv[0][r] = fminf(bo, v);
                }
                {
                    const float v  = p1a[r] + p1b[r];
                    const float bo = bestv[1][r];
                    bkk[1][r]   = (v < bo) ? kc : bkk[1][r];
                    secv[1][r]  = fminf(secv[1][r], fmaxf(bo, v));
                    bestv[1][r] = fminf(bo, v);
                }
            }
            fh0 = nh0; fh1 = nh1; fl0 = nl0; fl1 = nl1;
        }
        __syncthreads();             // reads done + next-tile stage drained
        cur ^= 1;
    }
#undef STAGE_J

    #pragma unroll
    for (int g = 0; g < 2; ++g) {
        #pragma unroll
        for (int r = 0; r < 4; ++r) {
            float b  = bestv[g][r], sc = secv[g][r];
            int   k  = bkk[g][r];
            #pragma unroll
            for (int off = 1; off < 16; off <<= 1) {
                const float ob = __shfl_xor(b, off);
                const int   ok = __shfl_xor(k, off);
                const float os = __shfl_xor(sc, off);
                const bool take = (ob < b) || (ob == b && ok < k);
                const float lose = take ? b : ob;
                sc = fminf(fminf(sc, os), lose);
                b  = take ? ob : b;
                k  = take ? ok : k;
            }
            if (col == 0) {
                const int q = Q0 + g * 16 + quad * 4 + r;
                kbest[q] = k;
                if (!(sc - b > WINHALF)) {              // ambiguous -> exact path
                    const int pos = atomicAdd(flagcnt, 1);
                    flaglist[pos] = q;
                }
            }
        }
    }
}

// ---- exact fp32 rescan, BLOCK per flagged query (verified, unchanged) ----
__global__ __launch_bounds__(256) void k_fix(const float* __restrict__ z,
                                             const float* __restrict__ cb,
                                             const float* __restrict__ ee,
                                             const int* __restrict__ flagcnt,
                                             const int* __restrict__ flaglist,
                                             int* __restrict__ kbest) {
    __shared__ float s_z[64];
    __shared__ float s_bv[4];
    __shared__ int   s_bk[4];
    const int tid  = threadIdx.x;
    const int lane = tid & 63;
    const int wave = tid >> 6;
    const int n = *flagcnt;

    for (int i = blockIdx.x; i < n; i += 1024) {
        const int q = flaglist[i];
        __syncthreads();               // s_z reuse guard across iterations
        if (tid < 16) ((float4*)s_z)[tid] = ((const float4*)(z + (size_t)q * C_))[tid];
        __syncthreads();

        float4 zn[16];
        float ss = 0.f;
        #pragma unroll
        for (int c4 = 0; c4 < 16; ++c4) {
            const float4 v = ((const float4*)s_z)[c4];
            zn[c4] = v;
            ss = fmaf(v.x, v.x, ss); ss = fmaf(v.y, v.y, ss);
            ss = fmaf(v.z, v.z, ss); ss = fmaf(v.w, v.w, ss);
        }
        const float nrm = fmaxf(sqrtf(ss), 1e-12f);
        #pragma unroll
        for (int c4 = 0; c4 < 16; ++c4) {
            zn[c4].x /= nrm; zn[c4].y /= nrm; zn[c4].z /= nrm; zn[c4].w /= nrm;
        }

        const int k0 = tid * 4;        // codes k0..k0+3 (k0+3 <= 1023)
        const float4* e0 = (const float4*)(cb + (size_t)(k0 + 1) * C_);
        const float4* e1 = (const float4*)(cb + (size_t)(k0 + 2) * C_);
        const float4* e2 = (const float4*)(cb + (size_t)(k0 + 3) * C_);
        const float4* e3 = (const float4*)(cb + (size_t)((k0 + 4 <= KE_) ? (k0 + 4) : KE_) * C_);
        float d0 = 0.f, d1 = 0.f, d2 = 0.f, d3 = 0.f;
        #pragma unroll
        for (int c4 = 0; c4 < 16; ++c4) {   // in-order fp32 chains
            const float4 x = zn[c4];
            const float4 a = e0[c4], b = e1[c4], c = e2[c4], d = e3[c4];
            d0 = fmaf(x.x, a.x, d0); d0 = fmaf(x.y, a.y, d0);
            d0 = fmaf(x.z, a.z, d0); d0 = fmaf(x.w, a.w, d0);
            d1 = fmaf(x.x, b.x, d1); d1 = fmaf(x.y, b.y, d1);
            d1 = fmaf(x.z, b.z, d1); d1 = fmaf(x.w, b.w, d1);
            d2 = fmaf(x.x, c.x, d2); d2 = fmaf(x.y, c.y, d2);
            d2 = fmaf(x.z, c.z, d2); d2 = fmaf(x.w, c.w, d2);
            d3 = fmaf(x.x, d.x, d3); d3 = fmaf(x.y, d.y, d3);
            d3 = fmaf(x.z, d.z, d3); d3 = fmaf(x.w, d.w, d3);
        }
        float bv = INFINITY;
        int   bk = 0;
        float v;
        v = fmaf(-2.f, d0, ee[k0 + 0]); if (v < bv) { bv = v; bk = k0 + 0; }
        v = fmaf(-2.f, d1, ee[k0 + 1]); if (v < bv) { bv = v; bk = k0 + 1; }
        v = fmaf(-2.f, d2, ee[k0 + 2]); if (v < bv) { bv = v; bk = k0 + 2; }
        v = fmaf(-2.f, d3, ee[k0 + 3]); if (v < bv) { bv = v; bk = k0 + 3; }

        #pragma unroll
        for (int off = 32; off > 0; off >>= 1) {
            const float ov = __shfl_down(bv, off);
            const int   ok = __shfl_down(bk, off);
            if (ov < bv || (ov == bv && ok < bk)) { bv = ov; bk = ok; }
        }
        if (lane == 0) { s_bv[wave] = bv; s_bk[wave] = bk; }
        __syncthreads();
        if (tid == 0) {
            float fb = s_bv[0]; int fk = s_bk[0];
            #pragma unroll
            for (int w = 1; w < 4; ++w) {
                if (s_bv[w] < fb || (s_bv[w] == fb && s_bk[w] < fk)) {
                    fb = s_bv[w]; fk = s_bk[w];
                }
            }
            kbest[q] = fk;
        }
    }
}

// ---- FUSED epilogue + compaction: blocks 0..15 = scan, 16..1039 = epi ----
// (verified R10: scan hides under epi; one less launch)
__global__ __launch_bounds__(256) void k_episcan(
    const float* __restrict__ z, const float* __restrict__ cb,
    const float* __restrict__ mask, const int* __restrict__ kbest,
    float* __restrict__ zqo,
    float* __restrict__ commit_part, float* __restrict__ valid_part,
    float* __restrict__ smooth_part,
    int* __restrict__ selpos, int* __restrict__ nst) {

    const int tid = threadIdx.x;

    if (blockIdx.x < 16) {
        // ---------------- scan path (verified R7 k_scan, verbatim) --------
        __shared__ int cnt[256];
        const int b = blockIdx.x;
        const int base = b * T_;
        const int t0 = tid * 16;

        int flags = 0, c = 0;
        int prev = (tid == 0) ? -1 : kbest[base + t0 - 1];
        #pragma unroll
        for (int i = 0; i < 16; ++i) {
            const int t = t0 + i;
            const int cur = kbest[base + t];
            const int is = (t == 0) ? 1
                         : ((cur != prev && mask[base + t] > 0.f) ? 1 : 0);
            flags |= is << i;
            c += is;
            prev = cur;
        }
        cnt[tid] = c;
        __syncthreads();
        for (int off = 1; off < 256; off <<= 1) {
            int add = (tid >= off) ? cnt[tid - off] : 0;
            __syncthreads();
            cnt[tid] += add;
            __syncthreads();
        }
        int pos = cnt[tid] - c;   // exclusive prefix
        #pragma unroll
        for (int i = 0; i < 16; ++i) {
            if ((flags >> i) & 1) selpos[base + pos++] = t0 + i;
        }
        if (tid == 255) nst[b] = cnt[255];
        return;
    }

    // ---------------- epi path (verified R7 k_epi, bid-shifted) -----------
    __shared__ float s_red[12];
    const int bid  = blockIdx.x - 16;
    const int lane = tid & 63;
    const int wave = tid >> 6;
    const int gt   = bid * 256 + tid;
    const int q    = gt >> 2;          // query index
    const int p    = gt & 3;           // 16-column chunk within query
    const int grp  = lane >> 2;        // 0..15 query-group within wave

    const int bi = kbest[q];
    const float m = mask[q];

    const float4* zp = (const float4*)(z + (size_t)q * C_ + p * 16);
    const float4* er = (const float4*)(cb + (size_t)(bi + 1) * C_ + p * 16);
    float4* zo = (float4*)(zqo + (size_t)q * C_ + p * 16);

    float4 zr[4];
    float ss = 0.f;
    #pragma unroll
    for (int i = 0; i < 4; ++i) {
        float4 v = zp[i];
        zr[i] = v;
        ss = fmaf(v.x, v.x, ss); ss = fmaf(v.y, v.y, ss);
        ss = fmaf(v.z, v.z, ss); ss = fmaf(v.w, v.w, ss);
    }
    // norm over the 4-lane group owning this query
    ss += __shfl_xor(ss, 1);
    ss += __shfl_xor(ss, 2);
    const float nrm = fmaxf(sqrtf(ss), 1e-12f);

    float commit = 0.f, sm = 0.f;
    float4 ov[4];
    #pragma unroll
    for (int c4 = 0; c4 < 4; ++c4) {
        const float z0 = zr[c4].x / nrm, z1 = zr[c4].y / nrm;
        const float z2 = zr[c4].z / nrm, z3 = zr[c4].w / nrm;
        const float4 e4 = er[c4];
        const float q0 = e4.x * m, q1 = e4.y * m, q2 = e4.z * m, q3 = e4.w * m;
        float4 o;
        o.x = (z0 + q0) - z0;              // straight-through forward value
        o.y = (z1 + q1) - z1;
        o.z = (z2 + q2) - z2;
        o.w = (z3 + q3) - z3;
        zo[c4] = o;
        ov[c4] = o;
        const float d0 = z0 - q0, d1 = z1 - q1, d2 = z2 - q2, d3 = z3 - q3;
        commit = fmaf(d0, d0, commit); commit = fmaf(d1, d1, commit);
        commit = fmaf(d2, d2, commit); commit = fmaf(d3, d3, commit);
    }
    commit *= m;

    // within-wave pairs (groups 0..14); shfl OOB returns own value -> diff 0
    float mnext = 0.f;
    if (grp != 15) mnext = mask[q + 1];    // q+1 in-range (grp 15 excluded)
    #pragma unroll
    for (int c4 = 0; c4 < 4; ++c4) {
        const float n0 = __shfl_down(ov[c4].x, 4);
        const float n1 = __shfl_down(ov[c4].y, 4);
        const float n2 = __shfl_down(ov[c4].z, 4);
        const float n3 = __shfl_down(ov[c4].w, 4);
        const float x0 = ov[c4].x - n0, x1 = ov[c4].y - n1;
        const float x2 = ov[c4].z - n2, x3 = ov[c4].w - n3;
        sm = fmaf(x0, x0, sm); sm = fmaf(x1, x1, sm);
        sm = fmaf(x2, x2, sm); sm = fmaf(x3, x3, sm);
    }
    sm *= mnext;

    // boundary pair (q, q+1) for group 15: recompute o(q+1) locally.
    if (grp == 15) {
        float mn = 0.f;
        if ((q & (T_ - 1)) != T_ - 1) mn = mask[q + 1];   // also guards q+1 OOB
        if (mn > 0.f) {
            const int bi2 = kbest[q + 1];
            const float4* zp2 = (const float4*)(z + (size_t)(q + 1) * C_ + p * 16);
            const float4* er2 = (const float4*)(cb + (size_t)(bi2 + 1) * C_ + p * 16);
            float4 zr2[4];
            float s2 = 0.f;
            #pragma unroll
            for (int i = 0; i < 4; ++i) {
                float4 v = zp2[i];
                zr2[i] = v;
                s2 = fmaf(v.x, v.x, s2); s2 = fmaf(v.y, v.y, s2);
                s2 = fmaf(v.z, v.z, s2); s2 = fmaf(v.w, v.w, s2);
            }
            s2 += __shfl_xor(s2, 1);
            s2 += __shfl_xor(s2, 2);
            const float nrm2 = fmaxf(sqrtf(s2), 1e-12f);
            float smb = 0.f;
            #pragma unroll
            for (int c4 = 0; c4 < 4; ++c4) {
                const float w0 = zr2[c4].x / nrm2, w1 = zr2[c4].y / nrm2;
                const float w2 = zr2[c4].z / nrm2, w3 = zr2[c4].w / nrm2;
                const float4 e4 = er2[c4];
                const float a0 = e4.x * mn, a1 = e4.y * mn;
                const float a2 = e4.z * mn, a3 = e4.w * mn;
                const float o0 = (w0 + a0) - w0;   // bitwise == zqo[q+1] chunk
                const float o1 = (w1 + a1) - w1;
                const float o2 = (w2 + a2) - w2;
                const float o3 = (w3 + a3) - w3;
                const float x0 = ov[c4].x - o0, x1 = ov[c4].y - o1;
                const float x2 = ov[c4].z - o2, x3 = ov[c4].w - o3;
                smb = fmaf(x0, x0, smb); smb = fmaf(x1, x1, smb);
                smb = fmaf(x2, x2, smb); smb = fmaf(x3, x3, smb);
            }
            sm = smb * mn;
        }
    }

    float vc = (p == 0) ? m : 0.f;     // count each query once
    #pragma unroll
    for (int off = 32; off > 0; off >>= 1) {
        commit += __shfl_down(commit, off);
        vc     += __shfl_down(vc, off);
        sm     += __shfl_down(sm, off);
    }
    if (lane == 0) { s_red[wave] = commit; s_red[4 + wave] = vc; s_red[8 + wave] = sm; }
    __syncthreads();
    if (tid == 0) {
        commit_part[bid] = s_red[0] + s_red[1] + s_red[2] + s_red[3];
        valid_part[bid]  = s_red[4] + s_red[5] + s_red[6] + s_red[7];
        smooth_part[bid] = s_red[8] + s_red[9] + s_red[10] + s_red[11];
    }
}

// ---- fused n_z_q gather + n_mask + selected_encodings + loss finalize ----
__global__ __launch_bounds__(256) void k_gsel(const float* __restrict__ zqo,
                                              const int* __restrict__ kbest,
                                              const int* __restrict__ selpos,
                                              const int* __restrict__ nst,
                                              const float* __restrict__ commit_part,
                                              const float* __restrict__ valid_part,
                                              const float* __restrict__ smooth_part,
                                              float* __restrict__ nzq,
                                              float* __restrict__ nmask,
                                              float* __restrict__ sel,
                                              float* __restrict__ out) {
    const int gid = blockIdx.x * 256 + threadIdx.x;   // float4 index
    const int b   = gid >> 16;          // T*C/4 = 65536 float4 per batch
    const int rem = gid & 65535;
    const int j   = rem >> 4;
    const int c4  = rem & 15;
    const int n   = nst[b];
    float4 v = make_float4(0.f, 0.f, 0.f, 0.f);
    int p = 0;
    if (j < n) {
        p = selpos[b * T_ + j];
        v = ((const float4*)zqo)[((size_t)b * T_ + p) * 16 + c4];
    }
    ((float4*)nzq)[gid] = v;
    if (c4 == 0) {
        float nm = 0.f, s = 0.f;
        if (j < n) { nm = 1.f; s = (float)(kbest[b * T_ + p] + 1); }
        nmask[b * T_ + j] = nm;
        sel[b * T_ + j]   = s;
    }

    // loss finalize: block 0 (partials ready: k_episcan precedes this)
    if (blockIdx.x == 0) {
        __shared__ double rc[256];
        __shared__ double rv[256];
        __shared__ double rs[256];
        const int tid = threadIdx.x;
        double sc = 0.0, sv = 0.0, ssm = 0.0;
        #pragma unroll
        for (int i = 0; i < 4; ++i) {
            sc  += (double)commit_part[tid + 256 * i];
            sv  += (double)valid_part[tid + 256 * i];
            ssm += (double)smooth_part[tid + 256 * i];
        }
        rc[tid] = sc; rv[tid] = sv; rs[tid] = ssm;
        __syncthreads();
        for (int off = 128; off > 0; off >>= 1) {
            if (tid < off) {
                rc[tid] += rc[tid + off];
                rv[tid] += rv[tid + off];
                rs[tid] += rs[tid + off];
            }
            __syncthreads();
        }
        if (tid == 0) {
            double valid = rv[0];
            out[0] = (float)(rs[0] / (valid - (double)B_));  // m1.sum() = valid - B
            out[1] = (float)(rc[0] / valid);
        }
    }
}

extern "C" void kernel_launch(void* const* d_in, const int* in_sizes, int n_in,
                              void* d_out, int out_size, void* d_ws, size_t ws_size,
                              hipStream_t stream) {
    const float* z    = (const float*)d_in[0];
    const float* cb   = (const float*)d_in[1];
    const float* mask = (const float*)d_in[2];
    float* out = (float*)d_out;
    char* ws = (char*)d_ws;

    int*            flagcnt     = (int*)(ws + 0);
    float*          ee          = (float*)(ws + 64);
    unsigned short* Eh          = (unsigned short*)(ws + 4224);
    unsigned short* El          = (unsigned short*)(ws + 135296);
    int*            kbest       = (int*)(ws + 266368);
    int*            selpos      = (int*)(ws + 528512);
    int*            nst         = (int*)(ws + 790656);
    float*          commit_part = (float*)(ws + 791680);
    float*          valid_part  = (float*)(ws + 795776);
    float*          smooth_part = (float*)(ws + 799872);
    int*            flaglist    = (int*)(ws + 804032);
    float*          ee2         = (float*)(ws + 1066176);

    float* zqo   = out + 2;
    float* nzq   = zqo + (size_t)BT_ * C_;
    float* nmask = nzq + (size_t)BT_ * C_;
    float* sel   = nmask + BT_;

    k_prep   <<<128,  256, 0, stream>>>(cb, ee, ee2, Eh, El, flagcnt);
    k_assign <<<512,  256, 0, stream>>>(z, Eh, El, ee2, kbest, flaglist, flagcnt);
    k_fix    <<<1024, 256, 0, stream>>>(z, cb, ee, flagcnt, flaglist, kbest);
    k_episcan<<<1040, 256, 0, stream>>>(z, cb, mask, kbest, zqo,
                                        commit_part, valid_part, smooth_part,
                                        selpos, nst);
    k_gsel   <<<4096, 256, 0, stream>>>(zqo, kbest, selpos, nst,
                                        commit_part, valid_part, smooth_part,
                                        nzq, nmask, sel, out);
}